// Round 8
// baseline (2902.577 us; speedup 1.0000x reference)
//
#include <hip/hip_runtime.h>
#include <hip/hip_bf16.h>

#define DIM 512
#define HEADS 8
#define DH 64
#define LM 256
#define NF 8192
#define BHN 16   // batch(2) * heads(8)

typedef __attribute__((ext_vector_type(8))) short short8;
typedef __attribute__((ext_vector_type(4))) float f32x4;

__device__ __forceinline__ float bf2f(unsigned short u) {
  return __uint_as_float((unsigned)u << 16);
}
__device__ __forceinline__ unsigned short f2bf(float x) {
  unsigned u = __float_as_uint(x);
  unsigned r = u + 0x7fffu + ((u >> 16) & 1u);
  return (unsigned short)(r >> 16);
}

// async global->LDS, 16B per lane; lds dest = wave-uniform base + lane*16
__device__ __forceinline__ void gl2lds16(const void* g, void* l) {
  __builtin_amdgcn_global_load_lds(
      (const __attribute__((address_space(1))) void*)g,
      (__attribute__((address_space(3))) void*)l, 16, 0, 0);
}

// ---------------- reduction helpers ----------------
__device__ __forceinline__ float waveReduceSum(float v) {
#pragma unroll
  for (int o = 1; o < 64; o <<= 1) v += __shfl_xor(v, o);
  return v;
}
__device__ __forceinline__ float waveReduceMax(float v) {
#pragma unroll
  for (int o = 1; o < 64; o <<= 1) v = fmaxf(v, __shfl_xor(v, o));
  return v;
}
__device__ __forceinline__ float blockReduceSum256(float v, float* sm) {
  v = waveReduceSum(v);
  int w = threadIdx.x >> 6;
  __syncthreads();
  if ((threadIdx.x & 63) == 0) sm[w] = v;
  __syncthreads();
  return sm[0] + sm[1] + sm[2] + sm[3];
}
__device__ __forceinline__ float blockReduceMax256(float v, float* sm) {
  v = waveReduceMax(v);
  int w = threadIdx.x >> 6;
  __syncthreads();
  if ((threadIdx.x & 63) == 0) sm[w] = v;
  __syncthreads();
  return fmaxf(fmaxf(sm[0], sm[1]), fmaxf(sm[2], sm[3]));
}

// ---------------- device-scope grid barrier (all blocks co-resident) ------
__device__ __forceinline__ void gbar(unsigned* cnt, unsigned target) {
  __syncthreads();  // drains each wave's vm/lgkm before barrier
  if (threadIdx.x == 0) {
    __threadfence();                 // release: L2 writeback (cross-XCD)
    atomicAdd(cnt, 1u);
    while (atomicAdd(cnt, 0u) < target) __builtin_amdgcn_s_sleep(2);
    __threadfence();                 // acquire: invalidate stale caches
  }
  __syncthreads();
}

// ---------------- casts ----------------
__global__ __launch_bounds__(256)
void cvt_bf16(const float* __restrict__ in, unsigned short* __restrict__ out,
              long long n) {
  long long i = ((long long)blockIdx.x * 256 + threadIdx.x) * 4;
  if (i + 3 < n) {
    float4 v = *(const float4*)&in[i];
    ushort4 o;
    o.x = f2bf(v.x); o.y = f2bf(v.y); o.z = f2bf(v.z); o.w = f2bf(v.w);
    *(ushort4*)&out[i] = o;
  } else {
    for (; i < n; i++) out[i] = f2bf(in[i]);
  }
}

// transpose+cast: in fp32 [K][N] -> out bf16 [N][K]
__global__ __launch_bounds__(256)
void cvt_transpose(const float* __restrict__ in, unsigned short* __restrict__ out,
                   int Kd, int Nd) {
  __shared__ float t[32][33];
  int x = threadIdx.x & 31, y = threadIdx.x >> 5;
#pragma unroll
  for (int i = 0; i < 32; i += 8) {
    int k = blockIdx.y * 32 + y + i, n = blockIdx.x * 32 + x;
    t[y + i][x] = in[(long long)k * Nd + n];
  }
  __syncthreads();
#pragma unroll
  for (int i = 0; i < 32; i += 8) {
    int n = blockIdx.x * 32 + y + i, k = blockIdx.y * 32 + x;
    out[(long long)n * Kd + k] = f2bf(t[x][y + i]);
  }
}

// VB [bh][n][d] bf16 -> VT [bh][d][n] bf16
__global__ __launch_bounds__(256)
void vt_transpose(const unsigned short* __restrict__ VB,
                  unsigned short* __restrict__ VT) {
  __shared__ unsigned short t[64][80];
  int bh = blockIdx.x >> 7, tile = blockIdx.x & 127;
  int n0 = tile * 64;
  int tid = threadIdx.x;
#pragma unroll
  for (int it = 0; it < 2; it++) {
    int s = it * 256 + tid;
    int nl = s >> 3, sg = s & 7;
    *(short8*)&t[nl][sg * 8] =
        *(const short8*)&VB[((long long)bh * NF + n0 + nl) * DH + sg * 8];
  }
  __syncthreads();
#pragma unroll
  for (int it = 0; it < 2; it++) {
    int s = it * 256 + tid;
    int dl = s >> 3, sg = s & 7;
    short8 v;
#pragma unroll
    for (int j = 0; j < 8; j++) ((unsigned short*)&v)[j] = t[sg * 8 + j][dl];
    *(short8*)&VT[((long long)bh * DH + dl) * NF + n0 + sg * 8] = v;
  }
}

// ---------------- zero fill ----------------
__global__ __launch_bounds__(256) void zero_f(float* __restrict__ p, int n) {
  int i = blockIdx.x * 256 + threadIdx.x;
  if (i < n) p[i] = 0.f;
}

// ---------------- cls row write ----------------
__global__ __launch_bounds__(256) void write_cls(const float* __restrict__ cls,
                                                 float* __restrict__ X) {
  int t = blockIdx.x * 256 + threadIdx.x;
  int b = t >> 9, c = t & 511;
  X[(long long)b * NF * DIM + c] = cls[c];
}

// ---------------- bf16 MFMA GEMM (projections), global_load_lds staging ----
// LDS union: Als/Bls staging (16KB) aliases the epilogue Ep buffer.
#define MG_RELU 1
#define MG_ADDC 2
#define MG_BIAS 4
// remap: 0 plain fp32, 1 embed scatter fp32, 2 qkv -> bf16 QB/KB/VB (vector)
__global__ __launch_bounds__(256)
void gemm_mfma(const unsigned short* __restrict__ A,
               const unsigned short* __restrict__ B,
               const float* __restrict__ bias, float* __restrict__ C,
               unsigned short* __restrict__ qkv, unsigned short* __restrict__ vbuf,
               int M, int N, int K, int flags, int remap) {
  __shared__ short8 smem[1024];  // 16 KB union
  short8 (*Als)[64] = (short8 (*)[64])smem;          // [8][64]
  short8 (*Bls)[64] = (short8 (*)[64])(smem + 512);  // [8][64]
  const int tid = threadIdx.x;
  const int lane = tid & 63, wave = tid >> 6;
  const int wm = wave >> 1, wn = wave & 1;
  const int m0 = blockIdx.y * 128, n0 = blockIdx.x * 128;
  const int r16 = lane & 15, quad = lane >> 4;
  const unsigned short* pa0 = A + (long long)(m0 + 32 * wave + r16) * K + quad * 8;
  const unsigned short* pa1 = A + (long long)(m0 + 32 * wave + 16 + r16) * K + quad * 8;
  const unsigned short* pb0 = B + (long long)(n0 + 32 * wave + r16) * K + quad * 8;
  const unsigned short* pb1 = B + (long long)(n0 + 32 * wave + 16 + r16) * K + quad * 8;
  f32x4 acc[4][4] = {};
  for (int k0 = 0; k0 < K; k0 += 32) {
    gl2lds16(pa0, &Als[2 * wave][0]);
    gl2lds16(pa1, &Als[2 * wave + 1][0]);
    gl2lds16(pb0, &Bls[2 * wave][0]);
    gl2lds16(pb1, &Bls[2 * wave + 1][0]);
    pa0 += 32; pa1 += 32; pb0 += 32; pb1 += 32;
    __syncthreads();
    short8 af[4], bfr[4];
#pragma unroll
    for (int mt = 0; mt < 4; mt++) af[mt] = Als[wm * 4 + mt][lane];
#pragma unroll
    for (int nt = 0; nt < 4; nt++) bfr[nt] = Bls[wn * 4 + nt][lane];
#pragma unroll
    for (int mt = 0; mt < 4; mt++)
#pragma unroll
      for (int nt = 0; nt < 4; nt++)
        acc[mt][nt] = __builtin_amdgcn_mfma_f32_16x16x32_bf16(
            af[mt], bfr[nt], acc[mt][nt], 0, 0, 0);
    __syncthreads();
  }
  if (remap == 2) {
    // Ep aliases the staging memory (safe: last __syncthreads() drained reads)
    unsigned short (*Ep)[32][64] = (unsigned short (*)[32][64])smem;
    int gn_base = n0 + wn * 64;
    int s = gn_base >> 9, hh = (gn_base >> 6) & 7;
    float scale = (s == 0) ? 0.125f : 1.f;
    unsigned short* basep =
        (s == 0) ? qkv : (s == 1) ? qkv + (long long)BHN * NF * DH : vbuf;
#pragma unroll
    for (int half = 0; half < 2; half++) {
      __builtin_amdgcn_s_waitcnt(0);
#pragma unroll
      for (int mt = half * 2; mt < half * 2 + 2; mt++)
#pragma unroll
        for (int nt = 0; nt < 4; nt++)
#pragma unroll
          for (int r = 0; r < 4; r++)
            Ep[wave][(mt & 1) * 16 + quad * 4 + r][nt * 16 + r16] =
                f2bf(acc[mt][nt][r] * scale);
      __builtin_amdgcn_s_waitcnt(0);
#pragma unroll
      for (int it = 0; it < 4; it++) {
        int idx = it * 64 + lane;
        int m_l = idx >> 3, sg = idx & 7;
        int gm = m0 + wm * 64 + half * 32 + m_l;
        int b = gm >> 13, n = gm & (NF - 1);
        int bh = b * HEADS + hh;
        short8 v = *(short8*)&Ep[wave][m_l][sg * 8];
        *(short8*)&basep[((long long)bh * NF + n) * DH + sg * 8] = v;
      }
    }
  } else {
#pragma unroll
    for (int mt = 0; mt < 4; mt++) {
#pragma unroll
      for (int nt = 0; nt < 4; nt++) {
#pragma unroll
        for (int r = 0; r < 4; r++) {
          int gm = m0 + wm * 64 + mt * 16 + quad * 4 + r;
          int gn = n0 + wn * 64 + nt * 16 + r16;
          if (gm >= M) continue;
          float v = acc[mt][nt][r];
          if (flags & MG_BIAS) v += bias[gn];
          long long idx;
          if (remap == 1) {
            int b = gm / 8191;
            int n = gm - b * 8191;
            idx = ((long long)(b * NF + 1 + n)) * DIM + gn;
          } else {
            idx = (long long)gm * N + gn;
          }
          if (flags & MG_ADDC) v += C[idx];
          if (flags & MG_RELU) v = fmaxf(v, 0.f);
          C[idx] = v;
        }
      }
    }
  }
}

// ---------------- fused attn1: wave=16 rows x 256 cols, in-wave softmax ----
__global__ __launch_bounds__(256)
void flash_attn1(const unsigned short* __restrict__ QB,
                 const unsigned short* __restrict__ KLB,
                 const unsigned short* __restrict__ WmB,
                 const unsigned short* __restrict__ XNC,
                 unsigned short* __restrict__ XNB2) {
  __shared__ unsigned short Plds[4][16][264];
  const int bh = blockIdx.y, b = bh >> 3, hh = bh & 7;
  const int tid = threadIdx.x, lane = tid & 63, wave = tid >> 6;
  const int r16 = lane & 15, quad = lane >> 4;
  const int m0w = blockIdx.x * 64 + wave * 16;
  const unsigned short* Aq = QB + (long long)bh * NF * DH;
  const unsigned short* Bk = KLB + (long long)bh * LM * DH;
  short8 af[2];
#pragma unroll
  for (int kc = 0; kc < 2; kc++)
    af[kc] = *(const short8*)&Aq[(long long)(m0w + r16) * DH + kc * 32 + quad * 8];
  f32x4 S[16] = {};
#pragma unroll
  for (int nt = 0; nt < 16; nt++) {
#pragma unroll
    for (int kc = 0; kc < 2; kc++) {
      short8 bb = *(const short8*)&Bk[(long long)(nt * 16 + r16) * DH + kc * 32 + quad * 8];
      S[nt] = __builtin_amdgcn_mfma_f32_16x16x32_bf16(af[kc], bb, S[nt], 0, 0, 0);
    }
  }
  float inv[4];
#pragma unroll
  for (int r = 0; r < 4; r++) {
    float m_ = S[0][r];
#pragma unroll
    for (int nt = 1; nt < 16; nt++) m_ = fmaxf(m_, S[nt][r]);
#pragma unroll
    for (int o = 1; o < 16; o <<= 1) m_ = fmaxf(m_, __shfl_xor(m_, o));
    float s_ = 0.f;
#pragma unroll
    for (int nt = 0; nt < 16; nt++) {
      float e = __expf(S[nt][r] - m_);
      S[nt][r] = e;
      s_ += e;
    }
#pragma unroll
    for (int o = 1; o < 16; o <<= 1) s_ += __shfl_xor(s_, o);
    inv[r] = 1.f / s_;
  }
#pragma unroll
  for (int nt = 0; nt < 16; nt++)
#pragma unroll
    for (int r = 0; r < 4; r++)
      Plds[wave][quad * 4 + r][nt * 16 + r16] = f2bf(S[nt][r] * inv[r]);
  __builtin_amdgcn_s_waitcnt(0);
  f32x4 O[4] = {};
#pragma unroll
  for (int kc = 0; kc < 8; kc++) {
    short8 a = *(short8*)&Plds[wave][r16][kc * 32 + quad * 8];
#pragma unroll
    for (int nt2 = 0; nt2 < 4; nt2++) {
      short8 bb = *(const short8*)&WmB[((long long)bh * DH + nt2 * 16 + r16) * LM +
                                       kc * 32 + quad * 8];
      O[nt2] = __builtin_amdgcn_mfma_f32_16x16x32_bf16(a, bb, O[nt2], 0, 0, 0);
    }
  }
#pragma unroll
  for (int nt2 = 0; nt2 < 4; nt2++)
#pragma unroll
    for (int r = 0; r < 4; r++) {
      int row = m0w + quad * 4 + r;
      int d = nt2 * 16 + r16;
      long long gi = ((long long)(b * NF + row)) * DIM + hh * DH + d;
      XNB2[gi] = f2bf(O[nt2][r] + bf2f(XNC[gi]));
    }
}

// ---------------- fused attn3 (flash-decode): partials over 8 KV chunks ----
__global__ __launch_bounds__(256)
void flash_attn3(const unsigned short* __restrict__ QLB,
                 const unsigned short* __restrict__ KB,
                 const unsigned short* __restrict__ VT,
                 float* __restrict__ Opart, float* __restrict__ Mpart,
                 float* __restrict__ Lpart) {
  __shared__ unsigned short Plds[4][16][136];
  const int bh = blockIdx.z, ks = blockIdx.y;
  const int tid = threadIdx.x, lane = tid & 63, wave = tid >> 6;
  const int r16 = lane & 15, quad = lane >> 4;
  const int m0w = blockIdx.x * 64 + wave * 16;
  const unsigned short* Aq = QLB + (long long)bh * LM * DH;
  const unsigned short* Bk = KB + (long long)bh * NF * DH;
  const unsigned short* Vt = VT + (long long)bh * DH * NF;
  short8 af[2];
#pragma unroll
  for (int kc = 0; kc < 2; kc++)
    af[kc] = *(const short8*)&Aq[(long long)(m0w + r16) * DH + kc * 32 + quad * 8];
  f32x4 O[4] = {};
  float rm[4] = {-1e30f, -1e30f, -1e30f, -1e30f};
  float rl[4] = {};
  for (int t = 0; t < 8; t++) {
    int kv0 = ks * 1024 + t * 128;
    f32x4 S[8] = {};
#pragma unroll
    for (int nt = 0; nt < 8; nt++) {
#pragma unroll
      for (int kc = 0; kc < 2; kc++) {
        short8 bb = *(const short8*)&Bk[(long long)(kv0 + nt * 16 + r16) * DH +
                                        kc * 32 + quad * 8];
        S[nt] = __builtin_amdgcn_mfma_f32_16x16x32_bf16(af[kc], bb, S[nt], 0, 0, 0);
      }
    }
#pragma unroll
    for (int r = 0; r < 4; r++) {
      float mt = S[0][r];
#pragma unroll
      for (int nt = 1; nt < 8; nt++) mt = fmaxf(mt, S[nt][r]);
#pragma unroll
      for (int o = 1; o < 16; o <<= 1) mt = fmaxf(mt, __shfl_xor(mt, o));
      float nm = fmaxf(rm[r], mt);
      float al = __expf(rm[r] - nm);
      rm[r] = nm;
      float s_ = 0.f;
#pragma unroll
      for (int nt = 0; nt < 8; nt++) {
        float e = __expf(S[nt][r] - nm);
        S[nt][r] = e;
        s_ += e;
      }
#pragma unroll
      for (int o = 1; o < 16; o <<= 1) s_ += __shfl_xor(s_, o);
      rl[r] = rl[r] * al + s_;
#pragma unroll
      for (int nt2 = 0; nt2 < 4; nt2++) O[nt2][r] *= al;
    }
#pragma unroll
    for (int nt = 0; nt < 8; nt++)
#pragma unroll
      for (int r = 0; r < 4; r++)
        Plds[wave][quad * 4 + r][nt * 16 + r16] = f2bf(S[nt][r]);
    __builtin_amdgcn_s_waitcnt(0);
#pragma unroll
    for (int kc2 = 0; kc2 < 4; kc2++) {
      short8 a = *(short8*)&Plds[wave][r16][kc2 * 32 + quad * 8];
#pragma unroll
      for (int nt2 = 0; nt2 < 4; nt2++) {
        short8 bb = *(const short8*)&Vt[(long long)(nt2 * 16 + r16) * NF + kv0 +
                                        kc2 * 32 + quad * 8];
        O[nt2] = __builtin_amdgcn_mfma_f32_16x16x32_bf16(a, bb, O[nt2], 0, 0, 0);
      }
    }
  }
  float* Ob = Opart + (((long long)ks * BHN + bh) * LM) * DH;
#pragma unroll
  for (int nt2 = 0; nt2 < 4; nt2++)
#pragma unroll
    for (int r = 0; r < 4; r++) {
      int row = m0w + quad * 4 + r;
      Ob[(long long)row * DH + nt2 * 16 + r16] = O[nt2][r];
    }
  if (r16 == 0) {
#pragma unroll
    for (int r = 0; r < 4; r++) {
      int row = m0w + quad * 4 + r;
      Mpart[((long long)ks * BHN + bh) * LM + row] = rm[r];
      Lpart[((long long)ks * BHN + bh) * LM + row] = rl[r];
    }
  }
}

__global__ __launch_bounds__(256)
void attn3_merge(const float* __restrict__ Opart, const float* __restrict__ Mpart,
                 const float* __restrict__ Lpart, float* __restrict__ O3) {
  int idx = blockIdx.x * 256 + threadIdx.x;  // 262144
  int bh = idx >> 14, rem = idx & 16383;
  int row = rem >> 6, d = rem & 63;
  float mg = -1e30f;
#pragma unroll
  for (int c = 0; c < 8; c++)
    mg = fmaxf(mg, Mpart[((long long)c * BHN + bh) * LM + row]);
  float L = 0.f, acc = 0.f;
#pragma unroll
  for (int c = 0; c < 8; c++) {
    float e = __expf(Mpart[((long long)c * BHN + bh) * LM + row] - mg);
    L += Lpart[((long long)c * BHN + bh) * LM + row] * e;
    acc += Opart[(((long long)c * BHN + bh) * LM + row) * DH + d] * e;
  }
  O3[((long long)bh * LM + row) * DH + d] = acc / L;
}

// ---------------- pinv step (bf16 MFMA): C = alpha*A@(bsign*B + ident*I) ---
__device__ __forceinline__ void pinv_step_bf16(
    const float* __restrict__ A, const float* __restrict__ B,
    float* __restrict__ C, int m0, int n0, float alpha, float ident,
    float bsign) {
  __shared__ unsigned short Als[64][40];
  __shared__ unsigned short Bls[64][40];
  const int tid = threadIdx.x;
  const int lane = tid & 63, wave = tid >> 6;
  const int wm2 = wave >> 1, wn2 = wave & 1;
  const int r16 = lane & 15, quad = lane >> 4;
  f32x4 acc[2][2] = {};
  for (int k0 = 0; k0 < 256; k0 += 32) {
#pragma unroll
    for (int it = 0; it < 2; it++) {
      int s = it * 256 + tid;
      int row = s >> 3, seg = s & 7;
      float4 v = *(const float4*)&A[(long long)(m0 + row) * 256 + k0 + seg * 4];
      ushort4 o;
      o.x = f2bf(v.x); o.y = f2bf(v.y); o.z = f2bf(v.z); o.w = f2bf(v.w);
      *(ushort4*)&Als[row][seg * 4] = o;
    }
#pragma unroll
    for (int it = 0; it < 2; it++) {
      int s = it * 256 + tid;
      int k = s >> 4, nc = (s & 15) * 4;
      float4 v = *(const float4*)&B[(long long)(k0 + k) * 256 + n0 + nc];
      float vv[4] = {v.x, v.y, v.z, v.w};
#pragma unroll
      for (int j = 0; j < 4; j++) {
        float bb = bsign * vv[j] + ((k0 + k) == (n0 + nc + j) ? ident : 0.f);
        Bls[nc + j][k] = f2bf(bb);
      }
    }
    __syncthreads();
    short8 af[2], bfr[2];
#pragma unroll
    for (int mt = 0; mt < 2; mt++)
      af[mt] = *(const short8*)&Als[wm2 * 32 + mt * 16 + r16][quad * 8];
#pragma unroll
    for (int nt = 0; nt < 2; nt++)
      bfr[nt] = *(const short8*)&Bls[wn2 * 32 + nt * 16 + r16][quad * 8];
#pragma unroll
    for (int mt = 0; mt < 2; mt++)
#pragma unroll
      for (int nt = 0; nt < 2; nt++)
        acc[mt][nt] = __builtin_amdgcn_mfma_f32_16x16x32_bf16(
            af[mt], bfr[nt], acc[mt][nt], 0, 0, 0);
    __syncthreads();
  }
#pragma unroll
  for (int mt = 0; mt < 2; mt++)
#pragma unroll
    for (int nt = 0; nt < 2; nt++)
#pragma unroll
      for (int r = 0; r < 4; r++)
        C[(long long)(m0 + wm2 * 32 + mt * 16 + quad * 4 + r) * 256 + n0 +
          wn2 * 32 + nt * 16 + r16] = alpha * acc[mt][nt][r];
}

// ---------------- pinv step (fp32 vector) ----------------
__device__ __forceinline__ void pinv_step_f32(
    const float* __restrict__ A, const float* __restrict__ B,
    float* __restrict__ C, int m0, int n0, float alpha, float ident,
    float bsign) {
  __shared__ float As[16][68];
  __shared__ float Bs[16][68];
  const int tid = threadIdx.x;
  const int tx = tid & 15, ty = tid >> 4;
  float acc[4][4] = {};
  for (int k0 = 0; k0 < 256; k0 += 16) {
    {
      int k = tid & 15, mB = tid >> 4;
#pragma unroll
      for (int i = 0; i < 4; i++) {
        int m = mB + i * 16;
        As[k][m] = A[(long long)(m0 + m) * 256 + k0 + k];
      }
    }
    {
      int n = tid & 63, kB = tid >> 6;
#pragma unroll
      for (int i = 0; i < 4; i++) {
        int k = kB + i * 4;
        float vb = B[(long long)(k0 + k) * 256 + n0 + n];
        Bs[k][n] = bsign * vb + ((k0 + k) == (n0 + n) ? ident : 0.f);
      }
    }
    __syncthreads();
#pragma unroll
    for (int k = 0; k < 16; k++) {
      float a[4], b[4];
#pragma unroll
      for (int i = 0; i < 4; i++) a[i] = As[k][ty * 4 + i];
#pragma unroll
      for (int j = 0; j < 4; j++) b[j] = Bs[k][tx * 4 + j];
#pragma unroll
      for (int i = 0; i < 4; i++)
#pragma unroll
        for (int j = 0; j < 4; j++) acc[i][j] = fmaf(a[i], b[j], acc[i][j]);
    }
    __syncthreads();
  }
#pragma unroll
  for (int i = 0; i < 4; i++)
#pragma unroll
    for (int j = 0; j < 4; j++)
      C[(long long)(m0 + ty * 4 + i) * 256 + n0 + tx * 4 + j] =
          alpha * acc[i][j];
}

// ---------------- whole pinv in one launch: 256 blocks (16 batch x 16 tile)
__global__ __launch_bounds__(256)
void pinv_all(const float* __restrict__ A2, float* __restrict__ ZA,
              float* __restrict__ ZB, float* __restrict__ P,
              float* __restrict__ T1, float* __restrict__ T2,
              const unsigned* __restrict__ RED, unsigned* __restrict__ cnt) {
  const int blk = blockIdx.x;
  const int batch = blk >> 4, tile = blk & 15;
  const int m0 = (tile >> 2) * 64, n0 = (tile & 3) * 64;
  const long long off = (long long)batch * 65536;
  unsigned bar = 0;
  {  // zinit: z0 = A2^T / (col*row)
    float scale = 1.f / (__uint_as_float(RED[0]) * __uint_as_float(RED[1]));
    const float* Ab = A2 + off;
    float* Zb = ZA + off;
    for (int u = threadIdx.x; u < 4096; u += 256) {
      int i = u >> 6, j = u & 63;
      Zb[(long long)(m0 + i) * 256 + n0 + j] =
          Ab[(long long)(n0 + j) * 256 + m0 + i] * scale;
    }
  }
  gbar(cnt, bar += 256);
  for (int it = 0; it < 6; it++) {
    float* zc = (it & 1) ? ZB : ZA;
    float* zn = (it & 1) ? ZA : ZB;
    if (it < 5) {  // bf16 MFMA iterations (Newton-Schulz self-corrects)
      pinv_step_bf16(A2 + off, zc + off, P + off, m0, n0, 1.f, 0.f, 1.f);
      gbar(cnt, bar += 256);
      pinv_step_bf16(P + off, P + off, T1 + off, m0, n0, 1.f, 7.f, -1.f);
      gbar(cnt, bar += 256);
      pinv_step_bf16(P + off, T1 + off, T2 + off, m0, n0, 1.f, 15.f, -1.f);
      gbar(cnt, bar += 256);
      pinv_step_bf16(zc + off, T2 + off, zn + off, m0, n0, 0.25f, 13.f, -1.f);
      gbar(cnt, bar += 256);
    } else {  // final iteration fp32
      pinv_step_f32(A2 + off, zc + off, P + off, m0, n0, 1.f, 0.f, 1.f);
      gbar(cnt, bar += 256);
      pinv_step_f32(P + off, P + off, T1 + off, m0, n0, 1.f, 7.f, -1.f);
      gbar(cnt, bar += 256);
      pinv_step_f32(P + off, T1 + off, T2 + off, m0, n0, 1.f, 15.f, -1.f);
      gbar(cnt, bar += 256);
      pinv_step_f32(zc + off, T2 + off, zn + off, m0, n0, 0.25f, 13.f, -1.f);
      // kernel end: dispatch boundary publishes zn (in ZA)
    }
  }
}

// ---------------- Wm = z @ O3, written transposed bf16 WmT[bh][d][k] -------
__global__ __launch_bounds__(256)
void wm_gemm(const float* __restrict__ Z, const float* __restrict__ O3,
             unsigned short* __restrict__ WmT) {
  const int batch = blockIdx.y;
  const int m0 = blockIdx.x * 64;
  const float* A = Z + (long long)batch * 65536;
  const float* B = O3 + (long long)batch * LM * DH;
  __shared__ float As[16][68];
  __shared__ float Bs[16][68];
  const int tid = threadIdx.x, tx = tid & 15, ty = tid >> 4;
  float acc[4][4] = {};
  for (int k0 = 0; k0 < 256; k0 += 16) {
    {
      int k = tid & 15, mB = tid >> 4;
#pragma unroll
      for (int i = 0; i < 4; i++) {
        int m = mB + i * 16;
        As[k][m] = A[(long long)(m0 + m) * 256 + k0 + k];
      }
    }
    {
      int n = tid & 63, kB = tid >> 6;
#pragma unroll
      for (int i = 0; i < 4; i++) {
        int k = kB + i * 4;
        Bs[k][n] = B[(long long)(k0 + k) * DH + n];
      }
    }
    __syncthreads();
#pragma unroll
    for (int k = 0; k < 16; k++) {
      float a[4], b[4];
#pragma unroll
      for (int i = 0; i < 4; i++) a[i] = As[k][ty * 4 + i];
#pragma unroll
      for (int j = 0; j < 4; j++) b[j] = Bs[k][tx * 4 + j];
#pragma unroll
      for (int i = 0; i < 4; i++)
#pragma unroll
        for (int j = 0; j < 4; j++) acc[i][j] = fmaf(a[i], b[j], acc[i][j]);
    }
    __syncthreads();
  }
#pragma unroll
  for (int i = 0; i < 4; i++)
#pragma unroll
    for (int j = 0; j < 4; j++)
      WmT[((long long)batch * DH + tx * 4 + j) * LM + m0 + ty * 4 + i] =
          f2bf(acc[i][j]);
}

// ---------------- row layernorm over 512 -> bf16 ----------------
__global__ __launch_bounds__(256)
void layernorm_rows_bf16(const float* __restrict__ X, const float* __restrict__ g,
                         const float* __restrict__ bt,
                         unsigned short* __restrict__ Y) {
  __shared__ float sm[4];
  long long r = blockIdx.x;
  const float* x = X + r * DIM;
  int t = threadIdx.x;
  float v0 = x[t], v1 = x[t + 256];
  float mu = blockReduceSum256(v0 + v1, sm) * (1.f / DIM);
  float d0 = v0 - mu, d1 = v1 - mu;
  float var = blockReduceSum256(d0 * d0 + d1 * d1, sm) * (1.f / DIM);
  float rs = 1.0f / sqrtf(var + 1e-5f);
  unsigned short* y = Y + r * DIM;
  y[t] = f2bf(d0 * rs * g[t] + bt[t]);
  y[t + 256] = f2bf(d1 * rs * g[t + 256] + bt[t + 256]);
}

// ---------------- landmark means from bf16 q,k ----------------
__global__ __launch_bounds__(64)
void landmarks_k(const unsigned short* __restrict__ q,
                 const unsigned short* __restrict__ k,
                 float* __restrict__ ql, float* __restrict__ kl,
                 unsigned short* __restrict__ qlb,
                 unsigned short* __restrict__ klb) {
  int bh = blockIdx.x >> 8, i = blockIdx.x & 255, d = threadIdx.x;
  long long base = ((long long)bh * NF + i * 32) * DH + d;
  float sq = 0.f, sk = 0.f;
#pragma unroll 4
  for (int l = 0; l < 32; l++) {
    sq += bf2f(q[base + (long long)l * DH]);
    sk += bf2f(k[base + (long long)l * DH]);
  }
  long long o = ((long long)bh * LM + i) * DH + d;
  float mq = sq * (1.f / 32.f), mk = sk * (1.f / 32.f);
  ql[o] = mq; kl[o] = mk;
  qlb[o] = f2bf(mq); klb[o] = f2bf(mk);
}

// ---------------- sim2 + row softmax -> attn2 (fp32) ----------------
__global__ __launch_bounds__(256)
void sim2_softmax(const float* __restrict__ ql, const float* __restrict__ kl,
                  float* __restrict__ a2) {
  __shared__ float qs[64];
  __shared__ float sm[4];
  int bh = blockIdx.x >> 8, i = blockIdx.x & 255, t = threadIdx.x;
  if (t < 64) qs[t] = ql[((long long)bh * LM + i) * DH + t];
  __syncthreads();
  const float* krow = kl + (long long)bh * LM * DH + (long long)t * DH;
  float s = 0.f;
#pragma unroll
  for (int d = 0; d < 64; d++) s += qs[d] * krow[d];
  float m = blockReduceMax256(s, sm);
  float e = expf(s - m);
  float sum = blockReduceSum256(e, sm);
  a2[((long long)bh * LM + i) * LM + t] = e / sum;
}

// ---------------- pinv global scale reduction ----------------
__global__ __launch_bounds__(256)
void pinv_reduce(const float* __restrict__ a2, unsigned* __restrict__ red) {
  __shared__ float sm[4];
  int bh = blockIdx.x, t = threadIdx.x;
  const float* A = a2 + (long long)bh * LM * LM;
  float cs = 0.f, rs = 0.f;
  for (int i = 0; i < 256; i++) cs += fabsf(A[i * 256 + t]);
  for (int j = 0; j < 256; j++) rs += fabsf(A[t * 256 + j]);
  float cm = blockReduceMax256(cs, sm);
  float rm = blockReduceMax256(rs, sm);
  if (t == 0) {
    atomicMax(&red[0], __float_as_uint(rm));
    atomicMax(&red[1], __float_as_uint(cm));
  }
}

// ---------------- depthwise conv residual -> bf16 scattered ----------------
__global__ __launch_bounds__(256)
void conv_res_bf16(const unsigned short* __restrict__ vt,
                   const float* __restrict__ cw,
                   unsigned short* __restrict__ out) {
  int bh = blockIdx.x >> 6, tile = blockIdx.x & 63;
  int b = bh >> 3, hh = bh & 7;
  int t = threadIdx.x;
  int d = t & 63, pg = t >> 6;
  float wr[33];
#pragma unroll
  for (int kk = 0; kk < 33; kk++) wr[kk] = cw[hh * 33 + kk];
  const unsigned short* src = &vt[((long long)bh * DH + d) * NF];
  int base = tile * 128 + pg * 32;
  int n0 = base - 16;
  float win[64];
#pragma unroll
  for (int jj = 0; jj < 8; jj++) {
    int c = n0 + jj * 8;
    if (c >= 0 && c + 7 < NF) {
      short8 v = *(const short8*)&src[c];
#pragma unroll
      for (int j = 0; j < 8; j++)
        win[jj * 8 + j] = bf2f((unsigned short)v[j]);
    } else {
#pragma unroll
      for (int j = 0; j < 8; j++) {
        int nn = c + j;
        win[jj * 8 + j] = (nn >= 0 && nn < NF) ? bf2f(src[nn]) : 0.f;
      }
    }
  }
  unsigned short* dst = &out[((long long)(b * NF + base)) * DIM + hh * DH + d];
#pragma unroll
  for (int p = 0; p < 32; p++) {
    float s = 0.f;
#pragma unroll
    for (int kk = 0; kk < 33; kk++) s = fmaf(wr[kk], win[p + kk], s);
    dst[(long long)p * DIM] = f2bf(s);
  }
}

// ---------------- final LN(row0) @ w2 + b2 ----------------
__global__ __launch_bounds__(256)
void final_head(const float* __restrict__ X, const float* __restrict__ g,
                const float* __restrict__ bt, const float* __restrict__ w2,
                const float* __restrict__ b2, float* __restrict__ out) {
  __shared__ float sm[4];
  int b = blockIdx.x, t = threadIdx.x;
  const float* row = X + (long long)b * NF * DIM;
  float v0 = row[t], v1 = row[t + 256];
  float mu = blockReduceSum256(v0 + v1, sm) * (1.f / DIM);
  float d0 = v0 - mu, d1 = v1 - mu;
  float var = blockReduceSum256(d0 * d0 + d1 * d1, sm) * (1.f / DIM);
  float rs = 1.0f / sqrtf(var + 1e-5f);
  float y0 = d0 * rs * g[t] + bt[t];
  float y1 = d1 * rs * g[t + 256] + bt[t + 256];
  float l0 = y0 * w2[t * 2 + 0] + y1 * w2[(t + 256) * 2 + 0];
  float l1 = y0 * w2[t * 2 + 1] + y1 * w2[(t + 256) * 2 + 1];
  l0 = blockReduceSum256(l0, sm);
  l1 = blockReduceSum256(l1, sm);
  if (t == 0) {
    out[b * 2 + 0] = l0 + b2[0];
    out[b * 2 + 1] = l1 + b2[1];
  }
}

extern "C" void kernel_launch(void* const* d_in, const int* in_sizes, int n_in,
                              void* d_out, int out_size, void* d_ws,
                              size_t ws_size, hipStream_t stream) {
  const float* h      = (const float*)d_in[0];
  const float* w1     = (const float*)d_in[1];
  const float* b1     = (const float*)d_in[2];
  const float* cls    = (const float*)d_in[3];
  const float* ln_g   = (const float*)d_in[4];
  const float* ln_b   = (const float*)d_in[5];
  const float* w_qkv  = (const float*)d_in[6];
  const float* w_out  = (const float*)d_in[7];
  const float* b_out  = (const float*)d_in[8];
  const float* conv_w = (const float*)d_in[9];
  const float* fn_g   = (const float*)d_in[10];
  const float* fn_b   = (const float*)d_in[11];
  const float* w2     = (const float*)d_in[12];
  const float* b2     = (const float*)d_in[13];

  float* ws = (float*)d_ws;
  const long long XSZ = (long long)2 * NF * DIM;      // 8388608
  const long long QSZ = (long long)BHN * NF * DH;     // 8388608
  float* X  = ws;                                     // 8.4M f
  unsigned short* STAGE = (unsigned short*)(X + XSZ); // 16.8M us
  unsigned short* HB   = STAGE;                 // embed bf16
  unsigned short* XNB1 = STAGE;                 // LN out bf16
  unsigned short* XNB2 = STAGE;                 // attn out bf16 (XNB1 dead)
  unsigned short* VB   = STAGE + XSZ;           // V row-major temp
  unsigned short* XNC  = STAGE + XSZ;           // conv bf16 (VB dead)
  unsigned short* QB = STAGE + 2 * XSZ;
  unsigned short* KB = QB + QSZ;
  unsigned short* VT = KB + QSZ;                // d-major
  float* QL = (float*)(VT + QSZ);
  float* KL = QL + 262144;
  unsigned short* QLB = (unsigned short*)(KL + 262144);
  unsigned short* KLB = QLB + 262144;
  float* A2 = (float*)(KLB + 262144);
  float* ZA = A2 + 1048576;
  float* ZB = ZA + 1048576;
  float* P  = ZB + 1048576;
  float* T1 = P + 1048576;
  float* T2 = T1 + 1048576;
  float* Opart = T2 + 1048576;                  // 2097152 f
  float* Mpart = Opart + 2097152;               // 32768 f
  float* Lpart = Mpart + 32768;                 // 32768 f
  float* O3 = Lpart + 32768;                    // 262144 f
  unsigned short* WmB = (unsigned short*)(O3 + 262144);  // 262144 us
  unsigned* RED = (unsigned*)(WmB + 262144);    // [red0, red1, cnt, pad]
  unsigned short* WT = (unsigned short*)(RED + 4);
  unsigned short* W1T = WT;                     // 524288 us
  unsigned short* WQ0 = W1T + 524288;           // 786432
  unsigned short* WQ1 = WQ0 + 786432;           // 786432
  unsigned short* WO0 = WQ1 + 786432;           // 262144
  unsigned short* WO1 = WO0 + 262144;           // 262144

  // ---- prologue: cls, h cast, all weight transposes, embed ----
  write_cls<<<4, 256, 0, stream>>>(cls, X);
  cvt_bf16<<<16382, 256, 0, stream>>>(h, HB, (long long)16382 * 1024);
  cvt_transpose<<<dim3(512 / 32, 1024 / 32), 256, 0, stream>>>(w1, W1T, 1024, 512);
  cvt_transpose<<<dim3(1536 / 32, 512 / 32), 256, 0, stream>>>(w_qkv, WQ0, 512, 1536);
  cvt_transpose<<<dim3(1536 / 32, 512 / 32), 256, 0, stream>>>(
      w_qkv + (long long)DIM * 1536, WQ1, 512, 1536);
  cvt_transpose<<<dim3(512 / 32, 512 / 32), 256, 0, stream>>>(w_out, WO0, 512, 512);
  cvt_transpose<<<dim3(512 / 32, 512 / 32), 256, 0, stream>>>(
      w_out + (long long)DIM * DIM, WO1, 512, 512);
  gemm_mfma<<<dim3(4, 128), 256, 0, stream>>>(HB, W1T, b1, X, nullptr, nullptr,
                                              16382, 512, 1024, MG_RELU | MG_BIAS, 1);

  for (int L = 0; L < 2; L++) {
    layernorm_rows_bf16<<<2 * NF, 256, 0, stream>>>(X, ln_g + L * DIM,
                                                    ln_b + L * DIM, XNB1);
    gemm_mfma<<<dim3(12, 128), 256, 0, stream>>>(XNB1, L ? WQ1 : WQ0, nullptr,
                                                 nullptr, QB, VB, 16384, 1536,
                                                 512, 0, 2);
    vt_transpose<<<BHN * 128, 256, 0, stream>>>(VB, VT);

    landmarks_k<<<BHN * LM, 64, 0, stream>>>(QB, KB, QL, KL, QLB, KLB);
    sim2_softmax<<<BHN * LM, 256, 0, stream>>>(QL, KL, A2);
    zero_f<<<1, 256, 0, stream>>>((float*)RED, 4);
    pinv_reduce<<<BHN, 256, 0, stream>>>(A2, RED);
    // whole Newton-Schulz loop in one persistent launch (grid barrier inside)
    pinv_all<<<256, 256, 0, stream>>>(A2, ZA, ZB, P, T1, T2, RED, RED + 2);
    // final z in ZA

    // ---- fused attn3: partials + merge -> O3 ----
    flash_attn3<<<dim3(4, 8, BHN), 256, 0, stream>>>(QLB, KB, VT, Opart, Mpart,
                                                     Lpart);
    attn3_merge<<<1024, 256, 0, stream>>>(Opart, Mpart, Lpart, O3);

    // WmT(bf16) = (z @ O3)^T
    wm_gemm<<<dim3(4, BHN), 256, 0, stream>>>(ZA, O3, WmB);

    // conv residual (bf16) into XNC
    conv_res_bf16<<<BHN * 64, 256, 0, stream>>>(VT, conv_w + L * 264, XNC);

    // ---- fused attn1: XNB2 = bf16(conv + attn1 @ Wm) ----
    flash_attn1<<<dim3(128, BHN), 256, 0, stream>>>(QB, KLB, WmB, XNC, XNB2);

    // ---- X += XNB2 @ w_out + b_out ----
    gemm_mfma<<<dim3(4, 128), 256, 0, stream>>>(XNB2, L ? WO1 : WO0,
                                                b_out + L * DIM, X, nullptr,
                                                nullptr, 16384, 512, 512,
                                                MG_ADDC | MG_BIAS, 0);
  }
  final_head<<<2, 256, 0, stream>>>(X, fn_g, fn_b, w2, b2, (float*)d_out);
}

// Round 9
// 1776.340 us; speedup vs baseline: 1.6340x; 1.6340x over previous
//
#include <hip/hip_runtime.h>
#include <hip/hip_bf16.h>

#define DIM 512
#define HEADS 8
#define DH 64
#define LM 256
#define NF 8192
#define BHN 16   // batch(2) * heads(8)

typedef __attribute__((ext_vector_type(8))) short short8;
typedef __attribute__((ext_vector_type(4))) float f32x4;

__device__ __forceinline__ float bf2f(unsigned short u) {
  return __uint_as_float((unsigned)u << 16);
}
__device__ __forceinline__ unsigned short f2bf(float x) {
  unsigned u = __float_as_uint(x);
  unsigned r = u + 0x7fffu + ((u >> 16) & 1u);
  return (unsigned short)(r >> 16);
}

// async global->LDS, 16B per lane; lds dest = wave-uniform base + lane*16
__device__ __forceinline__ void gl2lds16(const void* g, void* l) {
  __builtin_amdgcn_global_load_lds(
      (const __attribute__((address_space(1))) void*)g,
      (__attribute__((address_space(3))) void*)l, 16, 0, 0);
}

// ---------------- reduction helpers ----------------
__device__ __forceinline__ float waveReduceSum(float v) {
#pragma unroll
  for (int o = 1; o < 64; o <<= 1) v += __shfl_xor(v, o);
  return v;
}
__device__ __forceinline__ float waveReduceMax(float v) {
#pragma unroll
  for (int o = 1; o < 64; o <<= 1) v = fmaxf(v, __shfl_xor(v, o));
  return v;
}
__device__ __forceinline__ float blockReduceSum256(float v, float* sm) {
  v = waveReduceSum(v);
  int w = threadIdx.x >> 6;
  __syncthreads();
  if ((threadIdx.x & 63) == 0) sm[w] = v;
  __syncthreads();
  return sm[0] + sm[1] + sm[2] + sm[3];
}
__device__ __forceinline__ float blockReduceMax256(float v, float* sm) {
  v = waveReduceMax(v);
  int w = threadIdx.x >> 6;
  __syncthreads();
  if ((threadIdx.x & 63) == 0) sm[w] = v;
  __syncthreads();
  return fmaxf(fmaxf(sm[0], sm[1]), fmaxf(sm[2], sm[3]));
}

// ---------------- casts ----------------
__global__ __launch_bounds__(256)
void cvt_bf16(const float* __restrict__ in, unsigned short* __restrict__ out,
              long long n) {
  long long i = ((long long)blockIdx.x * 256 + threadIdx.x) * 4;
  if (i + 3 < n) {
    float4 v = *(const float4*)&in[i];
    ushort4 o;
    o.x = f2bf(v.x); o.y = f2bf(v.y); o.z = f2bf(v.z); o.w = f2bf(v.w);
    *(ushort4*)&out[i] = o;
  } else {
    for (; i < n; i++) out[i] = f2bf(in[i]);
  }
}

// transpose+cast: in fp32 [K][N] -> out bf16 [N][K]
__global__ __launch_bounds__(256)
void cvt_transpose(const float* __restrict__ in, unsigned short* __restrict__ out,
                   int Kd, int Nd) {
  __shared__ float t[32][33];
  int x = threadIdx.x & 31, y = threadIdx.x >> 5;
#pragma unroll
  for (int i = 0; i < 32; i += 8) {
    int k = blockIdx.y * 32 + y + i, n = blockIdx.x * 32 + x;
    t[y + i][x] = in[(long long)k * Nd + n];
  }
  __syncthreads();
#pragma unroll
  for (int i = 0; i < 32; i += 8) {
    int n = blockIdx.x * 32 + y + i, k = blockIdx.y * 32 + x;
    out[(long long)n * Kd + k] = f2bf(t[x][y + i]);
  }
}

// VB [bh][n][d] bf16 -> VT [bh][d][n] bf16
__global__ __launch_bounds__(256)
void vt_transpose(const unsigned short* __restrict__ VB,
                  unsigned short* __restrict__ VT) {
  __shared__ unsigned short t[64][80];
  int bh = blockIdx.x >> 7, tile = blockIdx.x & 127;
  int n0 = tile * 64;
  int tid = threadIdx.x;
#pragma unroll
  for (int it = 0; it < 2; it++) {
    int s = it * 256 + tid;
    int nl = s >> 3, sg = s & 7;
    *(short8*)&t[nl][sg * 8] =
        *(const short8*)&VB[((long long)bh * NF + n0 + nl) * DH + sg * 8];
  }
  __syncthreads();
#pragma unroll
  for (int it = 0; it < 2; it++) {
    int s = it * 256 + tid;
    int dl = s >> 3, sg = s & 7;
    short8 v;
#pragma unroll
    for (int j = 0; j < 8; j++) ((unsigned short*)&v)[j] = t[sg * 8 + j][dl];
    *(short8*)&VT[((long long)bh * DH + dl) * NF + n0 + sg * 8] = v;
  }
}

// ---------------- zero fill ----------------
__global__ __launch_bounds__(256) void zero_f(float* __restrict__ p, int n) {
  int i = blockIdx.x * 256 + threadIdx.x;
  if (i < n) p[i] = 0.f;
}

// ---------------- cls row write ----------------
__global__ __launch_bounds__(256) void write_cls(const float* __restrict__ cls,
                                                 float* __restrict__ X) {
  int t = blockIdx.x * 256 + threadIdx.x;
  int b = t >> 9, c = t & 511;
  X[(long long)b * NF * DIM + c] = cls[c];
}

// ---------------- bf16 MFMA GEMM (projections), global_load_lds staging ----
// LDS union: Als/Bls staging (16KB) aliases the epilogue Ep buffer.
#define MG_RELU 1
#define MG_ADDC 2
#define MG_BIAS 4
// remap: 0 plain fp32, 1 embed scatter fp32, 2 qkv -> bf16 QB/KB/VB (vector)
__global__ __launch_bounds__(256)
void gemm_mfma(const unsigned short* __restrict__ A,
               const unsigned short* __restrict__ B,
               const float* __restrict__ bias, float* __restrict__ C,
               unsigned short* __restrict__ qkv, unsigned short* __restrict__ vbuf,
               int M, int N, int K, int flags, int remap) {
  __shared__ short8 smem[1024];  // 16 KB union
  short8 (*Als)[64] = (short8 (*)[64])smem;          // [8][64]
  short8 (*Bls)[64] = (short8 (*)[64])(smem + 512);  // [8][64]
  const int tid = threadIdx.x;
  const int lane = tid & 63, wave = tid >> 6;
  const int wm = wave >> 1, wn = wave & 1;
  const int m0 = blockIdx.y * 128, n0 = blockIdx.x * 128;
  const int r16 = lane & 15, quad = lane >> 4;
  const unsigned short* pa0 = A + (long long)(m0 + 32 * wave + r16) * K + quad * 8;
  const unsigned short* pa1 = A + (long long)(m0 + 32 * wave + 16 + r16) * K + quad * 8;
  const unsigned short* pb0 = B + (long long)(n0 + 32 * wave + r16) * K + quad * 8;
  const unsigned short* pb1 = B + (long long)(n0 + 32 * wave + 16 + r16) * K + quad * 8;
  f32x4 acc[4][4] = {};
  for (int k0 = 0; k0 < K; k0 += 32) {
    gl2lds16(pa0, &Als[2 * wave][0]);
    gl2lds16(pa1, &Als[2 * wave + 1][0]);
    gl2lds16(pb0, &Bls[2 * wave][0]);
    gl2lds16(pb1, &Bls[2 * wave + 1][0]);
    pa0 += 32; pa1 += 32; pb0 += 32; pb1 += 32;
    __syncthreads();
    short8 af[4], bfr[4];
#pragma unroll
    for (int mt = 0; mt < 4; mt++) af[mt] = Als[wm * 4 + mt][lane];
#pragma unroll
    for (int nt = 0; nt < 4; nt++) bfr[nt] = Bls[wn * 4 + nt][lane];
#pragma unroll
    for (int mt = 0; mt < 4; mt++)
#pragma unroll
      for (int nt = 0; nt < 4; nt++)
        acc[mt][nt] = __builtin_amdgcn_mfma_f32_16x16x32_bf16(
            af[mt], bfr[nt], acc[mt][nt], 0, 0, 0);
    __syncthreads();
  }
  if (remap == 2) {
    // Ep aliases the staging memory (safe: last __syncthreads() drained reads)
    unsigned short (*Ep)[32][64] = (unsigned short (*)[32][64])smem;
    int gn_base = n0 + wn * 64;
    int s = gn_base >> 9, hh = (gn_base >> 6) & 7;
    float scale = (s == 0) ? 0.125f : 1.f;
    unsigned short* basep =
        (s == 0) ? qkv : (s == 1) ? qkv + (long long)BHN * NF * DH : vbuf;
#pragma unroll
    for (int half = 0; half < 2; half++) {
      __builtin_amdgcn_s_waitcnt(0);
#pragma unroll
      for (int mt = half * 2; mt < half * 2 + 2; mt++)
#pragma unroll
        for (int nt = 0; nt < 4; nt++)
#pragma unroll
          for (int r = 0; r < 4; r++)
            Ep[wave][(mt & 1) * 16 + quad * 4 + r][nt * 16 + r16] =
                f2bf(acc[mt][nt][r] * scale);
      __builtin_amdgcn_s_waitcnt(0);
#pragma unroll
      for (int it = 0; it < 4; it++) {
        int idx = it * 64 + lane;
        int m_l = idx >> 3, sg = idx & 7;
        int gm = m0 + wm * 64 + half * 32 + m_l;
        int b = gm >> 13, n = gm & (NF - 1);
        int bh = b * HEADS + hh;
        short8 v = *(short8*)&Ep[wave][m_l][sg * 8];
        *(short8*)&basep[((long long)bh * NF + n) * DH + sg * 8] = v;
      }
    }
  } else {
#pragma unroll
    for (int mt = 0; mt < 4; mt++) {
#pragma unroll
      for (int nt = 0; nt < 4; nt++) {
#pragma unroll
        for (int r = 0; r < 4; r++) {
          int gm = m0 + wm * 64 + mt * 16 + quad * 4 + r;
          int gn = n0 + wn * 64 + nt * 16 + r16;
          if (gm >= M) continue;
          float v = acc[mt][nt][r];
          if (flags & MG_BIAS) v += bias[gn];
          long long idx;
          if (remap == 1) {
            int b = gm / 8191;
            int n = gm - b * 8191;
            idx = ((long long)(b * NF + 1 + n)) * DIM + gn;
          } else {
            idx = (long long)gm * N + gn;
          }
          if (flags & MG_ADDC) v += C[idx];
          if (flags & MG_RELU) v = fmaxf(v, 0.f);
          C[idx] = v;
        }
      }
    }
  }
}

// ---------------- fused attn1: wave=16 rows x 256 cols, in-wave softmax ----
__global__ __launch_bounds__(256)
void flash_attn1(const unsigned short* __restrict__ QB,
                 const unsigned short* __restrict__ KLB,
                 const unsigned short* __restrict__ WmB,
                 const unsigned short* __restrict__ XNC,
                 unsigned short* __restrict__ XNB2) {
  __shared__ unsigned short Plds[4][16][264];
  const int bh = blockIdx.y, b = bh >> 3, hh = bh & 7;
  const int tid = threadIdx.x, lane = tid & 63, wave = tid >> 6;
  const int r16 = lane & 15, quad = lane >> 4;
  const int m0w = blockIdx.x * 64 + wave * 16;
  const unsigned short* Aq = QB + (long long)bh * NF * DH;
  const unsigned short* Bk = KLB + (long long)bh * LM * DH;
  short8 af[2];
#pragma unroll
  for (int kc = 0; kc < 2; kc++)
    af[kc] = *(const short8*)&Aq[(long long)(m0w + r16) * DH + kc * 32 + quad * 8];
  f32x4 S[16] = {};
#pragma unroll
  for (int nt = 0; nt < 16; nt++) {
#pragma unroll
    for (int kc = 0; kc < 2; kc++) {
      short8 bb = *(const short8*)&Bk[(long long)(nt * 16 + r16) * DH + kc * 32 + quad * 8];
      S[nt] = __builtin_amdgcn_mfma_f32_16x16x32_bf16(af[kc], bb, S[nt], 0, 0, 0);
    }
  }
  float inv[4];
#pragma unroll
  for (int r = 0; r < 4; r++) {
    float m_ = S[0][r];
#pragma unroll
    for (int nt = 1; nt < 16; nt++) m_ = fmaxf(m_, S[nt][r]);
#pragma unroll
    for (int o = 1; o < 16; o <<= 1) m_ = fmaxf(m_, __shfl_xor(m_, o));
    float s_ = 0.f;
#pragma unroll
    for (int nt = 0; nt < 16; nt++) {
      float e = __expf(S[nt][r] - m_);
      S[nt][r] = e;
      s_ += e;
    }
#pragma unroll
    for (int o = 1; o < 16; o <<= 1) s_ += __shfl_xor(s_, o);
    inv[r] = 1.f / s_;
  }
#pragma unroll
  for (int nt = 0; nt < 16; nt++)
#pragma unroll
    for (int r = 0; r < 4; r++)
      Plds[wave][quad * 4 + r][nt * 16 + r16] = f2bf(S[nt][r] * inv[r]);
  __builtin_amdgcn_s_waitcnt(0);
  f32x4 O[4] = {};
#pragma unroll
  for (int kc = 0; kc < 8; kc++) {
    short8 a = *(short8*)&Plds[wave][r16][kc * 32 + quad * 8];
#pragma unroll
    for (int nt2 = 0; nt2 < 4; nt2++) {
      short8 bb = *(const short8*)&WmB[((long long)bh * DH + nt2 * 16 + r16) * LM +
                                       kc * 32 + quad * 8];
      O[nt2] = __builtin_amdgcn_mfma_f32_16x16x32_bf16(a, bb, O[nt2], 0, 0, 0);
    }
  }
#pragma unroll
  for (int nt2 = 0; nt2 < 4; nt2++)
#pragma unroll
    for (int r = 0; r < 4; r++) {
      int row = m0w + quad * 4 + r;
      int d = nt2 * 16 + r16;
      long long gi = ((long long)(b * NF + row)) * DIM + hh * DH + d;
      XNB2[gi] = f2bf(O[nt2][r] + bf2f(XNC[gi]));
    }
}

// ---------------- fused attn3 (flash-decode): partials over 8 KV chunks ----
__global__ __launch_bounds__(256)
void flash_attn3(const unsigned short* __restrict__ QLB,
                 const unsigned short* __restrict__ KB,
                 const unsigned short* __restrict__ VT,
                 float* __restrict__ Opart, float* __restrict__ Mpart,
                 float* __restrict__ Lpart) {
  __shared__ unsigned short Plds[4][16][136];
  const int bh = blockIdx.z, ks = blockIdx.y;
  const int tid = threadIdx.x, lane = tid & 63, wave = tid >> 6;
  const int r16 = lane & 15, quad = lane >> 4;
  const int m0w = blockIdx.x * 64 + wave * 16;
  const unsigned short* Aq = QLB + (long long)bh * LM * DH;
  const unsigned short* Bk = KB + (long long)bh * NF * DH;
  const unsigned short* Vt = VT + (long long)bh * DH * NF;
  short8 af[2];
#pragma unroll
  for (int kc = 0; kc < 2; kc++)
    af[kc] = *(const short8*)&Aq[(long long)(m0w + r16) * DH + kc * 32 + quad * 8];
  f32x4 O[4] = {};
  float rm[4] = {-1e30f, -1e30f, -1e30f, -1e30f};
  float rl[4] = {};
  for (int t = 0; t < 8; t++) {
    int kv0 = ks * 1024 + t * 128;
    f32x4 S[8] = {};
#pragma unroll
    for (int nt = 0; nt < 8; nt++) {
#pragma unroll
      for (int kc = 0; kc < 2; kc++) {
        short8 bb = *(const short8*)&Bk[(long long)(kv0 + nt * 16 + r16) * DH +
                                        kc * 32 + quad * 8];
        S[nt] = __builtin_amdgcn_mfma_f32_16x16x32_bf16(af[kc], bb, S[nt], 0, 0, 0);
      }
    }
#pragma unroll
    for (int r = 0; r < 4; r++) {
      float mt = S[0][r];
#pragma unroll
      for (int nt = 1; nt < 8; nt++) mt = fmaxf(mt, S[nt][r]);
#pragma unroll
      for (int o = 1; o < 16; o <<= 1) mt = fmaxf(mt, __shfl_xor(mt, o));
      float nm = fmaxf(rm[r], mt);
      float al = __expf(rm[r] - nm);
      rm[r] = nm;
      float s_ = 0.f;
#pragma unroll
      for (int nt = 0; nt < 8; nt++) {
        float e = __expf(S[nt][r] - nm);
        S[nt][r] = e;
        s_ += e;
      }
#pragma unroll
      for (int o = 1; o < 16; o <<= 1) s_ += __shfl_xor(s_, o);
      rl[r] = rl[r] * al + s_;
#pragma unroll
      for (int nt2 = 0; nt2 < 4; nt2++) O[nt2][r] *= al;
    }
#pragma unroll
    for (int nt = 0; nt < 8; nt++)
#pragma unroll
      for (int r = 0; r < 4; r++)
        Plds[wave][quad * 4 + r][nt * 16 + r16] = f2bf(S[nt][r]);
    __builtin_amdgcn_s_waitcnt(0);
#pragma unroll
    for (int kc2 = 0; kc2 < 4; kc2++) {
      short8 a = *(short8*)&Plds[wave][r16][kc2 * 32 + quad * 8];
#pragma unroll
      for (int nt2 = 0; nt2 < 4; nt2++) {
        short8 bb = *(const short8*)&Vt[(long long)(nt2 * 16 + r16) * NF + kv0 +
                                        kc2 * 32 + quad * 8];
        O[nt2] = __builtin_amdgcn_mfma_f32_16x16x32_bf16(a, bb, O[nt2], 0, 0, 0);
      }
    }
  }
  float* Ob = Opart + (((long long)ks * BHN + bh) * LM) * DH;
#pragma unroll
  for (int nt2 = 0; nt2 < 4; nt2++)
#pragma unroll
    for (int r = 0; r < 4; r++) {
      int row = m0w + quad * 4 + r;
      Ob[(long long)row * DH + nt2 * 16 + r16] = O[nt2][r];
    }
  if (r16 == 0) {
#pragma unroll
    for (int r = 0; r < 4; r++) {
      int row = m0w + quad * 4 + r;
      Mpart[((long long)ks * BHN + bh) * LM + row] = rm[r];
      Lpart[((long long)ks * BHN + bh) * LM + row] = rl[r];
    }
  }
}

__global__ __launch_bounds__(256)
void attn3_merge(const float* __restrict__ Opart, const float* __restrict__ Mpart,
                 const float* __restrict__ Lpart, float* __restrict__ O3) {
  int idx = blockIdx.x * 256 + threadIdx.x;  // 262144
  int bh = idx >> 14, rem = idx & 16383;
  int row = rem >> 6, d = rem & 63;
  float mg = -1e30f;
#pragma unroll
  for (int c = 0; c < 8; c++)
    mg = fmaxf(mg, Mpart[((long long)c * BHN + bh) * LM + row]);
  float L = 0.f, acc = 0.f;
#pragma unroll
  for (int c = 0; c < 8; c++) {
    float e = __expf(Mpart[((long long)c * BHN + bh) * LM + row] - mg);
    L += Lpart[((long long)c * BHN + bh) * LM + row] * e;
    acc += Opart[(((long long)c * BHN + bh) * LM + row) * DH + d] * e;
  }
  O3[((long long)bh * LM + row) * DH + d] = acc / L;
}

// ---------------- z0 = attn2^T / (col*row) ----------------
__global__ __launch_bounds__(256)
void zinit(const float* __restrict__ a2, const unsigned* __restrict__ red,
           float* __restrict__ z) {
  float scale = 1.0f / (__uint_as_float(red[0]) * __uint_as_float(red[1]));
  long long idx = (long long)blockIdx.x * 256 + threadIdx.x;
  int bh = (int)(idx >> 16);
  int ij = (int)(idx & 65535);
  int i = ij >> 8, j = ij & 255;
  z[idx] = a2[((long long)bh << 16) + (j << 8) + i] * scale;
}

// ---------------- pinv 64-tile bf16 MFMA: C = alpha*A@(bsign*B + ident*I) ----
__global__ __launch_bounds__(256)
void pinv_gemm64(const float* __restrict__ A, const float* __restrict__ B,
                 float* __restrict__ C, float alpha, float ident, float bsign) {
  const int batch = blockIdx.z;
  A += (long long)batch * 65536;
  B += (long long)batch * 65536;
  C += (long long)batch * 65536;
  __shared__ unsigned short Als[64][40];
  __shared__ unsigned short Bls[64][40];
  const int tid = threadIdx.x;
  const int lane = tid & 63, wave = tid >> 6;
  const int wm2 = wave >> 1, wn2 = wave & 1;
  const int m0 = blockIdx.y * 64, n0 = blockIdx.x * 64;
  const int r16 = lane & 15, quad = lane >> 4;
  f32x4 acc[2][2] = {};
  for (int k0 = 0; k0 < 256; k0 += 32) {
#pragma unroll
    for (int it = 0; it < 2; it++) {
      int s = it * 256 + tid;
      int row = s >> 3, seg = s & 7;
      float4 v = *(const float4*)&A[(long long)(m0 + row) * 256 + k0 + seg * 4];
      ushort4 o;
      o.x = f2bf(v.x); o.y = f2bf(v.y); o.z = f2bf(v.z); o.w = f2bf(v.w);
      *(ushort4*)&Als[row][seg * 4] = o;
    }
#pragma unroll
    for (int it = 0; it < 2; it++) {
      int s = it * 256 + tid;
      int k = s >> 4, nc = (s & 15) * 4;
      float4 v = *(const float4*)&B[(long long)(k0 + k) * 256 + n0 + nc];
      float vv[4] = {v.x, v.y, v.z, v.w};
#pragma unroll
      for (int j = 0; j < 4; j++) {
        float bb = bsign * vv[j] + ((k0 + k) == (n0 + nc + j) ? ident : 0.f);
        Bls[nc + j][k] = f2bf(bb);
      }
    }
    __syncthreads();
    short8 af[2], bfr[2];
#pragma unroll
    for (int mt = 0; mt < 2; mt++)
      af[mt] = *(const short8*)&Als[wm2 * 32 + mt * 16 + r16][quad * 8];
#pragma unroll
    for (int nt = 0; nt < 2; nt++)
      bfr[nt] = *(const short8*)&Bls[wn2 * 32 + nt * 16 + r16][quad * 8];
#pragma unroll
    for (int mt = 0; mt < 2; mt++)
#pragma unroll
      for (int nt = 0; nt < 2; nt++)
        acc[mt][nt] = __builtin_amdgcn_mfma_f32_16x16x32_bf16(
            af[mt], bfr[nt], acc[mt][nt], 0, 0, 0);
    __syncthreads();
  }
#pragma unroll
  for (int mt = 0; mt < 2; mt++)
#pragma unroll
    for (int nt = 0; nt < 2; nt++)
#pragma unroll
      for (int r = 0; r < 4; r++)
        C[(long long)(m0 + wm2 * 32 + mt * 16 + quad * 4 + r) * 256 + n0 +
          wn2 * 32 + nt * 16 + r16] = alpha * acc[mt][nt][r];
}

// ---------------- batched GEMM (fp32: last pinv iter) ----------------
#define BG_BIDENT 16
__global__ __launch_bounds__(256)
void bgemm(const float* __restrict__ A, const float* __restrict__ B,
           float* __restrict__ C, int M, int N, int K,
           long long sA, long long sB, long long sC,
           float alpha, float ident, int flags) {
  const int batch = blockIdx.z;
  A += (long long)batch * sA;
  B += (long long)batch * sB;
  float* Cb = C + (long long)batch * sC;
  __shared__ float As[16][68];
  __shared__ float Bs[16][68];
  const int tid = threadIdx.x;
  const int tx = tid & 15, ty = tid >> 4;
  const int m0 = blockIdx.y * 64, n0 = blockIdx.x * 64;
  float acc[4][4] = {};
  for (int k0 = 0; k0 < K; k0 += 16) {
    {
      int k = tid & 15;
      int mBase = tid >> 4;
#pragma unroll
      for (int i = 0; i < 4; i++) {
        int m = mBase + i * 16;
        int gm = m0 + m;
        As[k][m] = (gm < M) ? A[(long long)gm * K + (k0 + k)] : 0.f;
      }
    }
    {
      int n = tid & 63;
      int kBase = tid >> 6;
#pragma unroll
      for (int i = 0; i < 4; i++) {
        int k = kBase + i * 4;
        int gn = n0 + n;
        float vb = (gn < N) ? B[(long long)(k0 + k) * N + gn] : 0.f;
        if (flags & BG_BIDENT) vb = ident * ((k0 + k) == gn ? 1.f : 0.f) - vb;
        Bs[k][n] = vb;
      }
    }
    __syncthreads();
#pragma unroll
    for (int k = 0; k < 16; k++) {
      float a[4], b[4];
#pragma unroll
      for (int i = 0; i < 4; i++) a[i] = As[k][ty * 4 + i];
#pragma unroll
      for (int j = 0; j < 4; j++) b[j] = Bs[k][tx * 4 + j];
#pragma unroll
      for (int i = 0; i < 4; i++)
#pragma unroll
        for (int j = 0; j < 4; j++) acc[i][j] = fmaf(a[i], b[j], acc[i][j]);
    }
    __syncthreads();
  }
#pragma unroll
  for (int i = 0; i < 4; i++) {
    int gm = m0 + ty * 4 + i;
    if (gm >= M) continue;
#pragma unroll
    for (int j = 0; j < 4; j++) {
      int gn = n0 + tx * 4 + j;
      if (gn >= N) continue;
      Cb[(long long)gm * N + gn] = alpha * acc[i][j];
    }
  }
}

// ---------------- Wm = z @ O3, written transposed bf16 WmT[bh][d][k] -------
__global__ __launch_bounds__(256)
void wm_gemm(const float* __restrict__ Z, const float* __restrict__ O3,
             unsigned short* __restrict__ WmT) {
  const int batch = blockIdx.y;
  const int m0 = blockIdx.x * 64;
  const float* A = Z + (long long)batch * 65536;
  const float* B = O3 + (long long)batch * LM * DH;
  __shared__ float As[16][68];
  __shared__ float Bs[16][68];
  const int tid = threadIdx.x, tx = tid & 15, ty = tid >> 4;
  float acc[4][4] = {};
  for (int k0 = 0; k0 < 256; k0 += 16) {
    {
      int k = tid & 15, mB = tid >> 4;
#pragma unroll
      for (int i = 0; i < 4; i++) {
        int m = mB + i * 16;
        As[k][m] = A[(long long)(m0 + m) * 256 + k0 + k];
      }
    }
    {
      int n = tid & 63, kB = tid >> 6;
#pragma unroll
      for (int i = 0; i < 4; i++) {
        int k = kB + i * 4;
        Bs[k][n] = B[(long long)(k0 + k) * DH + n];
      }
    }
    __syncthreads();
#pragma unroll
    for (int k = 0; k < 16; k++) {
      float a[4], b[4];
#pragma unroll
      for (int i = 0; i < 4; i++) a[i] = As[k][ty * 4 + i];
#pragma unroll
      for (int j = 0; j < 4; j++) b[j] = Bs[k][tx * 4 + j];
#pragma unroll
      for (int i = 0; i < 4; i++)
#pragma unroll
        for (int j = 0; j < 4; j++) acc[i][j] = fmaf(a[i], b[j], acc[i][j]);
    }
    __syncthreads();
  }
#pragma unroll
  for (int i = 0; i < 4; i++)
#pragma unroll
    for (int j = 0; j < 4; j++)
      WmT[((long long)batch * DH + tx * 4 + j) * LM + m0 + ty * 4 + i] =
          f2bf(acc[i][j]);
}

// ---------------- row layernorm over 512 -> bf16 ----------------
__global__ __launch_bounds__(256)
void layernorm_rows_bf16(const float* __restrict__ X, const float* __restrict__ g,
                         const float* __restrict__ bt,
                         unsigned short* __restrict__ Y) {
  __shared__ float sm[4];
  long long r = blockIdx.x;
  const float* x = X + r * DIM;
  int t = threadIdx.x;
  float v0 = x[t], v1 = x[t + 256];
  float mu = blockReduceSum256(v0 + v1, sm) * (1.f / DIM);
  float d0 = v0 - mu, d1 = v1 - mu;
  float var = blockReduceSum256(d0 * d0 + d1 * d1, sm) * (1.f / DIM);
  float rs = 1.0f / sqrtf(var + 1e-5f);
  unsigned short* y = Y + r * DIM;
  y[t] = f2bf(d0 * rs * g[t] + bt[t]);
  y[t + 256] = f2bf(d1 * rs * g[t + 256] + bt[t + 256]);
}

// ---------------- landmark means from bf16 q,k ----------------
__global__ __launch_bounds__(64)
void landmarks_k(const unsigned short* __restrict__ q,
                 const unsigned short* __restrict__ k,
                 float* __restrict__ ql, float* __restrict__ kl,
                 unsigned short* __restrict__ qlb,
                 unsigned short* __restrict__ klb) {
  int bh = blockIdx.x >> 8, i = blockIdx.x & 255, d = threadIdx.x;
  long long base = ((long long)bh * NF + i * 32) * DH + d;
  float sq = 0.f, sk = 0.f;
#pragma unroll 4
  for (int l = 0; l < 32; l++) {
    sq += bf2f(q[base + (long long)l * DH]);
    sk += bf2f(k[base + (long long)l * DH]);
  }
  long long o = ((long long)bh * LM + i) * DH + d;
  float mq = sq * (1.f / 32.f), mk = sk * (1.f / 32.f);
  ql[o] = mq; kl[o] = mk;
  qlb[o] = f2bf(mq); klb[o] = f2bf(mk);
}

// ---------------- sim2 + row softmax -> attn2 (fp32) ----------------
__global__ __launch_bounds__(256)
void sim2_softmax(const float* __restrict__ ql, const float* __restrict__ kl,
                  float* __restrict__ a2) {
  __shared__ float qs[64];
  __shared__ float sm[4];
  int bh = blockIdx.x >> 8, i = blockIdx.x & 255, t = threadIdx.x;
  if (t < 64) qs[t] = ql[((long long)bh * LM + i) * DH + t];
  __syncthreads();
  const float* krow = kl + (long long)bh * LM * DH + (long long)t * DH;
  float s = 0.f;
#pragma unroll
  for (int d = 0; d < 64; d++) s += qs[d] * krow[d];
  float m = blockReduceMax256(s, sm);
  float e = expf(s - m);
  float sum = blockReduceSum256(e, sm);
  a2[((long long)bh * LM + i) * LM + t] = e / sum;
}

// ---------------- pinv global scale reduction ----------------
__global__ __launch_bounds__(256)
void pinv_reduce(const float* __restrict__ a2, unsigned* __restrict__ red) {
  __shared__ float sm[4];
  int bh = blockIdx.x, t = threadIdx.x;
  const float* A = a2 + (long long)bh * LM * LM;
  float cs = 0.f, rs = 0.f;
  for (int i = 0; i < 256; i++) cs += fabsf(A[i * 256 + t]);
  for (int j = 0; j < 256; j++) rs += fabsf(A[t * 256 + j]);
  float cm = blockReduceMax256(cs, sm);
  float rm = blockReduceMax256(rs, sm);
  if (t == 0) {
    atomicMax(&red[0], __float_as_uint(rm));
    atomicMax(&red[1], __float_as_uint(cm));
  }
}

// ---------------- depthwise conv residual -> bf16 scattered ----------------
__global__ __launch_bounds__(256)
void conv_res_bf16(const unsigned short* __restrict__ vt,
                   const float* __restrict__ cw,
                   unsigned short* __restrict__ out) {
  int bh = blockIdx.x >> 6, tile = blockIdx.x & 63;
  int b = bh >> 3, hh = bh & 7;
  int t = threadIdx.x;
  int d = t & 63, pg = t >> 6;
  float wr[33];
#pragma unroll
  for (int kk = 0; kk < 33; kk++) wr[kk] = cw[hh * 33 + kk];
  const unsigned short* src = &vt[((long long)bh * DH + d) * NF];
  int base = tile * 128 + pg * 32;
  int n0 = base - 16;
  float win[64];
#pragma unroll
  for (int jj = 0; jj < 8; jj++) {
    int c = n0 + jj * 8;
    if (c >= 0 && c + 7 < NF) {
      short8 v = *(const short8*)&src[c];
#pragma unroll
      for (int j = 0; j < 8; j++)
        win[jj * 8 + j] = bf2f((unsigned short)v[j]);
    } else {
#pragma unroll
      for (int j = 0; j < 8; j++) {
        int nn = c + j;
        win[jj * 8 + j] = (nn >= 0 && nn < NF) ? bf2f(src[nn]) : 0.f;
      }
    }
  }
  unsigned short* dst = &out[((long long)(b * NF + base)) * DIM + hh * DH + d];
#pragma unroll
  for (int p = 0; p < 32; p++) {
    float s = 0.f;
#pragma unroll
    for (int kk = 0; kk < 33; kk++) s = fmaf(wr[kk], win[p + kk], s);
    dst[(long long)p * DIM] = f2bf(s);
  }
}

// ---------------- final LN(row0) @ w2 + b2 ----------------
__global__ __launch_bounds__(256)
void final_head(const float* __restrict__ X, const float* __restrict__ g,
                const float* __restrict__ bt, const float* __restrict__ w2,
                const float* __restrict__ b2, float* __restrict__ out) {
  __shared__ float sm[4];
  int b = blockIdx.x, t = threadIdx.x;
  const float* row = X + (long long)b * NF * DIM;
  float v0 = row[t], v1 = row[t + 256];
  float mu = blockReduceSum256(v0 + v1, sm) * (1.f / DIM);
  float d0 = v0 - mu, d1 = v1 - mu;
  float var = blockReduceSum256(d0 * d0 + d1 * d1, sm) * (1.f / DIM);
  float rs = 1.0f / sqrtf(var + 1e-5f);
  float y0 = d0 * rs * g[t] + bt[t];
  float y1 = d1 * rs * g[t + 256] + bt[t + 256];
  float l0 = y0 * w2[t * 2 + 0] + y1 * w2[(t + 256) * 2 + 0];
  float l1 = y0 * w2[t * 2 + 1] + y1 * w2[(t + 256) * 2 + 1];
  l0 = blockReduceSum256(l0, sm);
  l1 = blockReduceSum256(l1, sm);
  if (t == 0) {
    out[b * 2 + 0] = l0 + b2[0];
    out[b * 2 + 1] = l1 + b2[1];
  }
}

extern "C" void kernel_launch(void* const* d_in, const int* in_sizes, int n_in,
                              void* d_out, int out_size, void* d_ws,
                              size_t ws_size, hipStream_t stream) {
  const float* h      = (const float*)d_in[0];
  const float* w1     = (const float*)d_in[1];
  const float* b1     = (const float*)d_in[2];
  const float* cls    = (const float*)d_in[3];
  const float* ln_g   = (const float*)d_in[4];
  const float* ln_b   = (const float*)d_in[5];
  const float* w_qkv  = (const float*)d_in[6];
  const float* w_out  = (const float*)d_in[7];
  const float* b_out  = (const float*)d_in[8];
  const float* conv_w = (const float*)d_in[9];
  const float* fn_g   = (const float*)d_in[10];
  const float* fn_b   = (const float*)d_in[11];
  const float* w2     = (const float*)d_in[12];
  const float* b2     = (const float*)d_in[13];

  float* ws = (float*)d_ws;
  const long long XSZ = (long long)2 * NF * DIM;      // 8388608
  const long long QSZ = (long long)BHN * NF * DH;     // 8388608
  float* X  = ws;                                     // 8.4M f
  unsigned short* STAGE = (unsigned short*)(X + XSZ); // 16.8M us
  unsigned short* HB   = STAGE;                 // embed bf16
  unsigned short* XNB1 = STAGE;                 // LN out bf16
  unsigned short* XNB2 = STAGE;                 // attn out bf16 (XNB1 dead)
  unsigned short* VB   = STAGE + XSZ;           // V row-major temp
  unsigned short* XNC  = STAGE + XSZ;           // conv bf16 (VB dead)
  unsigned short* QB = STAGE + 2 * XSZ;
  unsigned short* KB = QB + QSZ;
  unsigned short* VT = KB + QSZ;                // d-major
  float* QL = (float*)(VT + QSZ);
  float* KL = QL + 262144;
  unsigned short* QLB = (unsigned short*)(KL + 262144);
  unsigned short* KLB = QLB + 262144;
  float* A2 = (float*)(KLB + 262144);
  float* ZA = A2 + 1048576;
  float* ZB = ZA + 1048576;
  float* P  = ZB + 1048576;
  float* T1 = P + 1048576;
  float* T2 = T1 + 1048576;
  float* Opart = T2 + 1048576;                  // 2097152 f
  float* Mpart = Opart + 2097152;               // 32768 f
  float* Lpart = Mpart + 32768;                 // 32768 f
  float* O3 = Lpart + 32768;                    // 262144 f
  unsigned short* WmB = (unsigned short*)(O3 + 262144);  // 262144 us
  unsigned* RED = (unsigned*)(WmB + 262144);    // [red0, red1, pad, pad]
  unsigned short* WT = (unsigned short*)(RED + 4);
  unsigned short* W1T = WT;                     // 524288 us
  unsigned short* WQ0 = W1T + 524288;           // 786432
  unsigned short* WQ1 = WQ0 + 786432;           // 786432
  unsigned short* WO0 = WQ1 + 786432;           // 262144
  unsigned short* WO1 = WO0 + 262144;           // 262144

  // ---- prologue: cls, h cast, all weight transposes, embed ----
  write_cls<<<4, 256, 0, stream>>>(cls, X);
  cvt_bf16<<<16382, 256, 0, stream>>>(h, HB, (long long)16382 * 1024);
  cvt_transpose<<<dim3(512 / 32, 1024 / 32), 256, 0, stream>>>(w1, W1T, 1024, 512);
  cvt_transpose<<<dim3(1536 / 32, 512 / 32), 256, 0, stream>>>(w_qkv, WQ0, 512, 1536);
  cvt_transpose<<<dim3(1536 / 32, 512 / 32), 256, 0, stream>>>(
      w_qkv + (long long)DIM * 1536, WQ1, 512, 1536);
  cvt_transpose<<<dim3(512 / 32, 512 / 32), 256, 0, stream>>>(w_out, WO0, 512, 512);
  cvt_transpose<<<dim3(512 / 32, 512 / 32), 256, 0, stream>>>(
      w_out + (long long)DIM * DIM, WO1, 512, 512);
  gemm_mfma<<<dim3(4, 128), 256, 0, stream>>>(HB, W1T, b1, X, nullptr, nullptr,
                                              16382, 512, 1024, MG_RELU | MG_BIAS, 1);

  for (int L = 0; L < 2; L++) {
    layernorm_rows_bf16<<<2 * NF, 256, 0, stream>>>(X, ln_g + L * DIM,
                                                    ln_b + L * DIM, XNB1);
    gemm_mfma<<<dim3(12, 128), 256, 0, stream>>>(XNB1, L ? WQ1 : WQ0, nullptr,
                                                 nullptr, QB, VB, 16384, 1536,
                                                 512, 0, 2);
    vt_transpose<<<BHN * 128, 256, 0, stream>>>(VB, VT);

    landmarks_k<<<BHN * LM, 64, 0, stream>>>(QB, KB, QL, KL, QLB, KLB);
    sim2_softmax<<<BHN * LM, 256, 0, stream>>>(QL, KL, A2);
    zero_f<<<1, 256, 0, stream>>>((float*)RED, 4);
    pinv_reduce<<<BHN, 256, 0, stream>>>(A2, RED);
    zinit<<<4096, 256, 0, stream>>>(A2, RED, ZA);
    for (int it = 0; it < 6; it++) {
      float* zc = (it & 1) ? ZB : ZA;
      float* zn = (it & 1) ? ZA : ZB;
      if (it < 5) {  // bf16 MFMA iterations (Newton-Schulz self-corrects)
        pinv_gemm64<<<dim3(4, 4, BHN), 256, 0, stream>>>(A2, zc, P, 1.f, 0.f, 1.f);
        pinv_gemm64<<<dim3(4, 4, BHN), 256, 0, stream>>>(P, P, T1, 1.f, 7.f, -1.f);
        pinv_gemm64<<<dim3(4, 4, BHN), 256, 0, stream>>>(P, T1, T2, 1.f, 15.f, -1.f);
        pinv_gemm64<<<dim3(4, 4, BHN), 256, 0, stream>>>(zc, T2, zn, 0.25f, 13.f, -1.f);
      } else {  // final iteration fp32
        bgemm<<<dim3(4, 4, BHN), 256, 0, stream>>>(A2, zc, P, 256, 256, 256,
                                                   65536, 65536, 65536, 1.f, 0.f, 0);
        bgemm<<<dim3(4, 4, BHN), 256, 0, stream>>>(P, P, T1, 256, 256, 256,
                                                   65536, 65536, 65536, 1.f, 7.f,
                                                   BG_BIDENT);
        bgemm<<<dim3(4, 4, BHN), 256, 0, stream>>>(P, T1, T2, 256, 256, 256,
                                                   65536, 65536, 65536, 1.f, 15.f,
                                                   BG_BIDENT);
        bgemm<<<dim3(4, 4, BHN), 256, 0, stream>>>(zc, T2, zn, 256, 256, 256,
                                                   65536, 65536, 65536, 0.25f,
                                                   13.f, BG_BIDENT);
      }
    }
    // final z in ZA

    // ---- fused attn3: partials + merge -> O3 ----
    flash_attn3<<<dim3(4, 8, BHN), 256, 0, stream>>>(QLB, KB, VT, Opart, Mpart,
                                                     Lpart);
    attn3_merge<<<1024, 256, 0, stream>>>(Opart, Mpart, Lpart, O3);

    // WmT(bf16) = (z @ O3)^T
    wm_gemm<<<dim3(4, BHN), 256, 0, stream>>>(ZA, O3, WmB);

    // conv residual (bf16) into XNC
    conv_res_bf16<<<BHN * 64, 256, 0, stream>>>(VT, conv_w + L * 264, XNC);

    // ---- fused attn1: XNB2 = bf16(conv + attn1 @ Wm) ----
    flash_attn1<<<dim3(128, BHN), 256, 0, stream>>>(QB, KLB, WmB, XNC, XNB2);

    // ---- X += XNB2 @ w_out + b_out ----
    gemm_mfma<<<dim3(4, 128), 256, 0, stream>>>(XNB2, L ? WO1 : WO0,
                                                b_out + L * DIM, X, nullptr,
                                                nullptr, 16384, 512, 512,
                                                MG_ADDC | MG_BIAS, 0);
  }
  final_head<<<2, 256, 0, stream>>>(X, fn_g, fn_b, w2, b2, (float*)d_out);
}